// Round 12
// baseline (2503.345 us; speedup 1.0000x reference)
//
#include <hip/hip_runtime.h>
#include <math.h>

#define B_ 1024
#define T_ 128
#define H_ 2048
#define C_ 10

typedef __bf16 bf16_t;
typedef __bf16 bf16x8 __attribute__((ext_vector_type(8)));
typedef __bf16 bf16x4 __attribute__((ext_vector_type(4)));
typedef float f32x4 __attribute__((ext_vector_type(4)));

// Static device storage: bf16 h ping-pong (8 MB), bf16 W_hh^T (8 MB),
// per-(t,bm,chunk) readiness flags (XCD-local fine-grained handoff).
__device__ __align__(16) bf16_t g_hb[2][(size_t)B_ * H_];
__device__ __align__(16) bf16_t g_whhT[(size_t)H_ * H_];
__device__ int g_fc[T_ * 256];   // [t][bm(8)][chunk(32)]; t=0 seeded to 1

// AUX: cache policy. 0 = default; 1 = sc0 (force L1 miss -> read XCD L2).
template <int AUX>
__device__ __forceinline__ void gload16(const bf16_t* g, bf16_t* l) {
    __builtin_amdgcn_global_load_lds(
        (const __attribute__((address_space(1))) void*)g,
        (__attribute__((address_space(3))) void*)l, 16, 0, AUX);
}

// Counted-vmcnt barrier: retire oldest pipeline stage without draining.
template <int VM>
__device__ __forceinline__ void wait_vm_barrier() {
    asm volatile("s_waitcnt vmcnt(%0)\n\ts_barrier" :: "n"(VM) : "memory");
}

// One-time: W_hhT[n][k] = bf16(W_hh[k][n]) — B operand must be K-contiguous.
__global__ __launch_bounds__(256) void prep_whhT(const float* __restrict__ Whh) {
    __shared__ float tile[32][33];
    const int i  = threadIdx.x >> 3;
    const int j4 = (threadIdx.x & 7) * 4;
    const int r0 = blockIdx.y * 32;
    const int c0 = blockIdx.x * 32;
    f32x4 v = *(const f32x4*)(Whh + (size_t)(r0 + i) * H_ + c0 + j4);
    tile[i][j4 + 0] = v[0]; tile[i][j4 + 1] = v[1];
    tile[i][j4 + 2] = v[2]; tile[i][j4 + 3] = v[3];
    __syncthreads();
    bf16x4 o;
#pragma unroll
    for (int r = 0; r < 4; ++r) o[r] = (bf16_t)tile[j4 + r][i];
    *(bf16x4*)&g_whhT[(size_t)(c0 + i) * H_ + r0 + j4] = o;
}

// t = 0: h = tanh(x[:,0]*W_hx + b_h); also (re)initialize the flags.
__global__ __launch_bounds__(256) void rnn_init(const float* __restrict__ x,
                                                const float* __restrict__ Whx,
                                                const float* __restrict__ bh) {
    if (blockIdx.x < 16) {
        const int base = blockIdx.x * 2048;
        for (int k = 0; k < 8; ++k) {
            const int i = base + k * 256 + threadIdx.x;
            g_fc[i] = (i < 256) ? 1 : 0;   // t=0 ready; t>=1 cleared
        }
    }
    const int gid = blockIdx.x * 256 + threadIdx.x;
    const int row = gid >> 9;
    const int col = (gid & 511) << 2;
    const float xv = x[(size_t)row * T_];
    f32x4 w = *(const f32x4*)&Whx[col];
    f32x4 b = *(const f32x4*)&bh[col];
    bf16x4 o;
#pragma unroll
    for (int j = 0; j < 4; ++j) o[j] = (bf16_t)tanhf(fmaf(xv, w[j], b[j]));
    *(bf16x4*)&g_hb[0][(size_t)row * H_ + col] = o;
}

// Persistent RNN, XCD-local sync with PER-CHUNK flags: writer (bm,bn) of
// step t-1 produces exactly A-chunk bn; the reader checks chunk c's flag
// only when staging it (5 iters before compute) -> the once-per-step
// straggler convoy becomes a graduated pipeline. Flag loads are issued 4
// regions early (asm global_load_dword sc0) so they retire under the same
// vmcnt schedule as the staging loads -- zero added waits in the fast path.
// Per step: 128x64 tile, BK=64 (32 iters), 4 waves x 64x32, 6-stage LDS
// ring, zig-zag K order (L2 LRU reuse of W_hh^T across steps).
__global__ __launch_bounds__(256, 1) void rnn_persist(const float* __restrict__ x,
                                                      const float* __restrict__ Whx,
                                                      const float* __restrict__ bh) {
    extern __shared__ __align__(16) bf16_t smem[];
    bf16_t* As = smem;                 // 6 stages x 8192 elems (16 KB)
    bf16_t* Bs = smem + 6 * 8192;      // 6 stages x 4096 elems (8 KB)

    const int tid  = threadIdx.x;
    const int lane = tid & 63;
    const int wave = tid >> 6;
    const int li  = blockIdx.x;
    const int bm  = li & 7;                          // == XCD (blk%8 map)
    const int bn  = li >> 3;                         // 0..31

    const int wm = (wave & 1) * 64, wn = (wave >> 1) * 32;
    const int fr = lane & 15, fq = lane >> 4;

    // Staging: linear slot s holds row s>>3, lds-chunk s&7;
    // global chunk = (s&7) ^ (row&7)  (8-row spread -> 2-way frag reads).
    const int rA = tid >> 3;                         // 0..31
    const int cg = (tid & 7) ^ (rA & 7);
    const size_t aofsg = (size_t)(bm * 128 + rA) * H_ + cg * 8;
    const bf16_t* const gb0 = g_whhT + (size_t)(bn * 64 + rA) * H_ + cg * 8;

#define ISSUE_A(SLOT)                                                    \
    do {                                                                 \
        gload16<1>(gpa,            As + (SLOT) * 8192 + tid * 8);        \
        gload16<1>(gpa + 32 * H_,  As + (SLOT) * 8192 + (tid + 256) * 8);\
        gload16<1>(gpa + 64 * H_,  As + (SLOT) * 8192 + (tid + 512) * 8);\
        gload16<1>(gpa + 96 * H_,  As + (SLOT) * 8192 + (tid + 768) * 8);\
        gpa += kstep;                                                    \
    } while (0)
#define ISSUE_B(SLOT)                                                    \
    do {                                                                 \
        gload16<0>(gpb,            Bs + (SLOT) * 4096 + tid * 8);        \
        gload16<0>(gpb + 32 * H_,  Bs + (SLOT) * 4096 + (tid + 256) * 8);\
        gpb += kstep;                                                    \
    } while (0)
#define ISSUE_AB(SLOT) do { ISSUE_A(SLOT); ISSUE_B(SLOT); } while (0)

    // frag offsets (elems): row*64 + ((cc*4+fq) ^ (row&7))*8; row&7 == fr&7.
    const int xr0 = (fq ^ (fr & 7)) * 8;
    const int xr1 = ((4 + fq) ^ (fr & 7)) * 8;
    int aoff[4][2], boff[2][2];
#pragma unroll
    for (int i = 0; i < 4; ++i) {
        aoff[i][0] = (wm + i * 16 + fr) * 64 + xr0;
        aoff[i][1] = (wm + i * 16 + fr) * 64 + xr1;
    }
#pragma unroll
    for (int j = 0; j < 2; ++j) {
        boff[j][0] = (wn + j * 16 + fr) * 64 + xr0;
        boff[j][1] = (wn + j * 16 + fr) * 64 + xr1;
    }

#define COMPUTE(SLOT)                                                       \
    {                                                                       \
        _Pragma("unroll")                                                   \
        for (int cc = 0; cc < 2; ++cc) {                                    \
            bf16x8 af[4], bfv[2];                                           \
            _Pragma("unroll")                                               \
            for (int j = 0; j < 2; ++j)                                     \
                bfv[j] = *(const bf16x8*)(Bs + (SLOT) * 4096 + boff[j][cc]);\
            _Pragma("unroll")                                               \
            for (int i = 0; i < 4; ++i)                                     \
                af[i] = *(const bf16x8*)(As + (SLOT) * 8192 + aoff[i][cc]); \
            _Pragma("unroll")                                               \
            for (int i = 0; i < 4; ++i)                                     \
                _Pragma("unroll")                                           \
                for (int j = 0; j < 2; ++j)                                 \
                    acc[i][j] = __builtin_amdgcn_mfma_f32_16x16x32_bf16(    \
                        af[i], bfv[j], acc[i][j], 0, 0, 0);                 \
        }                                                                   \
    }

// Region u: wait (constant W derived from FIFO position so both the staged
// tile and the early-issued flag are retired); validate flag for the chunk
// about to be staged (slow-path spin only if the writer is late); issue the
// next flag-load 4 regions ahead into the same VGPR; stage; compute.
#define REG(W, FV, CHUNK, ISLOT, CSLOT, DOFG, FGC)                          \
    wait_vm_barrier<W>();                                                   \
    if (FV == 0) {                                                          \
        const int* ck = fb + fdir * (CHUNK);                                \
        for (;;) {                                                          \
            asm volatile("global_load_dword %0, %1, off sc0\n\t"            \
                         "s_waitcnt vmcnt(0)"                               \
                         : "=v"(FV) : "v"(ck) : "memory");                  \
            if (FV != 0) break;                                             \
            __builtin_amdgcn_s_sleep(1);                                    \
        }                                                                   \
    }                                                                       \
    if (DOFG)                                                               \
        asm volatile("global_load_dword %0, %1, off sc0"                    \
                     : "=v"(FV) : "v"(fb + fdir * (FGC)) : "memory");       \
    ISSUE_AB(ISLOT);                                                        \
    COMPUTE(CSLOT);

    // epilogue constants (step-invariant)
    float wv[2], bv[2];
    int xbase[4];
#pragma unroll
    for (int j = 0; j < 2; ++j) {
        const int col = bn * 64 + wn + j * 16 + fr;
        wv[j] = Whx[col];
        bv[j] = bh[col];
    }
#pragma unroll
    for (int i = 0; i < 4; ++i)
        xbase[i] = (bm * 128 + wm + i * 16 + fq * 4) * T_;

    for (int t = 1; t < T_; ++t) {
        const bf16_t* __restrict__ Abuf = g_hb[(t - 1) & 1];
        bf16_t* __restrict__ hn = g_hb[t & 1];
        // zig-zag: odd steps walk K from the top (L2 LRU tail is hot)
        const int odd   = t & 1;
        const int koff  = odd ? (H_ - 64) : 0;
        const int kstep = odd ? -64 : 64;
        const bf16_t* gpa = Abuf + aofsg + koff;
        const bf16_t* gpb = gb0 + koff;
        // flag base for step t-1, walked in zig-zag chunk order
        const int* fb  = &g_fc[(t - 1) * 256 + bm * 32 + (odd ? 31 : 0)];
        const int fdir = odd ? -1 : 1;

        // B stages 0..4 (immutable) before any dependency wait.
        ISSUE_B(0); ISSUE_B(1); ISSUE_B(2); ISSUE_B(3); ISSUE_B(4);
        // flag prefetch for chunks 5..8 (drained by the spins below)
        int fv0, fv1, fv2, fv3;
        asm volatile("global_load_dword %0, %1, off sc0" : "=v"(fv0) : "v"(fb + fdir * 5) : "memory");
        asm volatile("global_load_dword %0, %1, off sc0" : "=v"(fv1) : "v"(fb + fdir * 6) : "memory");
        asm volatile("global_load_dword %0, %1, off sc0" : "=v"(fv2) : "v"(fb + fdir * 7) : "memory");
        asm volatile("global_load_dword %0, %1, off sc0" : "=v"(fv3) : "v"(fb + fdir * 8) : "memory");
        // chunks 0..4: plain spin (writers of the first 5 chunks only)
        for (int c = 0; c < 5; ++c) {
            while (__hip_atomic_load(fb + fdir * c, __ATOMIC_RELAXED,
                                     __HIP_MEMORY_SCOPE_AGENT) == 0)
                __builtin_amdgcn_s_sleep(1);
        }
        ISSUE_A(0); ISSUE_A(1); ISSUE_A(2); ISSUE_A(3); ISSUE_A(4);

        f32x4 acc[4][2];
#pragma unroll
        for (int i = 0; i < 4; ++i)
#pragma unroll
            for (int j = 0; j < 2; ++j) acc[i][j] = (f32x4)(0.f);

        //    W   FV   CHK ISL CSL FG? FGC
        REG(16, fv0,  5,  5,  0, 1,  9)
        REG(19, fv1,  6,  0,  1, 1, 10)
        REG(22, fv2,  7,  1,  2, 1, 11)
        REG(25, fv3,  8,  2,  3, 1, 12)
        REG(27, fv0,  9,  3,  4, 1, 13)
        REG(27, fv1, 10,  4,  5, 1, 14)
        REG(27, fv2, 11,  5,  0, 1, 15)
        REG(27, fv3, 12,  0,  1, 1, 16)
        REG(27, fv0, 13,  1,  2, 1, 17)
        REG(27, fv1, 14,  2,  3, 1, 18)
        REG(27, fv2, 15,  3,  4, 1, 19)
        REG(27, fv3, 16,  4,  5, 1, 20)
        REG(27, fv0, 17,  5,  0, 1, 21)
        REG(27, fv1, 18,  0,  1, 1, 22)
        REG(27, fv2, 19,  1,  2, 1, 23)
        REG(27, fv3, 20,  2,  3, 1, 24)
        REG(27, fv0, 21,  3,  4, 1, 25)
        REG(27, fv1, 22,  4,  5, 1, 26)
        REG(27, fv2, 23,  5,  0, 1, 27)
        REG(27, fv3, 24,  0,  1, 1, 28)
        REG(27, fv0, 25,  1,  2, 1, 29)
        REG(27, fv1, 26,  2,  3, 1, 30)
        REG(27, fv2, 27,  3,  4, 1, 31)
        REG(27, fv3, 28,  4,  5, 0,  0)
        REG(26, fv0, 29,  5,  0, 0,  0)
        REG(25, fv1, 30,  0,  1, 0,  0)
        REG(24, fv2, 31,  1,  2, 0,  0)
        // drain: stages 27..31 (slots 3,4,5,0,1)
        wait_vm_barrier<24>(); COMPUTE(3);
        wait_vm_barrier<18>(); COMPUTE(4);
        wait_vm_barrier<12>(); COMPUTE(5);
        wait_vm_barrier<6>();  COMPUTE(0);
        wait_vm_barrier<0>();  COMPUTE(1);

        // epilogue: + x_t*W_hx + b_h, tanh, bf16 store
#pragma unroll
        for (int i = 0; i < 4; ++i) {
            const int row0 = bm * 128 + wm + i * 16 + fq * 4;
            float xv[4];
#pragma unroll
            for (int r = 0; r < 4; ++r) xv[r] = x[xbase[i] + r * T_ + t];
#pragma unroll
            for (int j = 0; j < 2; ++j) {
                const int col = bn * 64 + wn + j * 16 + fr;
#pragma unroll
                for (int r = 0; r < 4; ++r)
                    hn[(size_t)(row0 + r) * H_ + col] =
                        (bf16_t)tanhf(acc[i][j][r] + xv[r] * wv[j] + bv[j]);
            }
        }

        // publish: drain stores to L2, join waves, set this block's flag.
        asm volatile("s_waitcnt vmcnt(0)" ::: "memory");
        __syncthreads();
        if (tid == 0)
            __hip_atomic_store(&g_fc[t * 256 + bm * 32 + bn], 1,
                               __ATOMIC_RELAXED, __HIP_MEMORY_SCOPE_AGENT);
    }
#undef REG
#undef COMPUTE
#undef ISSUE_AB
#undef ISSUE_B
#undef ISSUE_A
}

// p = h_T @ W_ph + b_p : one wave per batch row, fp32 accumulate.
__global__ __launch_bounds__(64) void rnn_proj(const float* __restrict__ Wph,
                                               const float* __restrict__ bp,
                                               float* __restrict__ out, int sb) {
    const int b = blockIdx.x;
    const int l = threadIdx.x;
    const bf16_t* h = g_hb[sb] + (size_t)b * H_;
    float acc[C_];
#pragma unroll
    for (int c = 0; c < C_; ++c) acc[c] = 0.f;
    for (int k = l; k < H_; k += 64) {
        const float hv = (float)h[k];
#pragma unroll
        for (int c = 0; c < C_; ++c)
            acc[c] = fmaf(hv, Wph[k * C_ + c], acc[c]);
    }
#pragma unroll
    for (int off = 32; off > 0; off >>= 1)
#pragma unroll
        for (int c = 0; c < C_; ++c) acc[c] += __shfl_down(acc[c], off);
    if (l == 0) {
#pragma unroll
        for (int c = 0; c < C_; ++c) out[b * C_ + c] = acc[c] + bp[c];
    }
}

extern "C" void kernel_launch(void* const* d_in, const int* in_sizes, int n_in,
                              void* d_out, int out_size, void* d_ws, size_t ws_size,
                              hipStream_t stream) {
    const float* x   = (const float*)d_in[0];   // [1024,128]
    const float* Whx = (const float*)d_in[1];   // [1,2048]
    const float* Whh = (const float*)d_in[2];   // [2048,2048]
    const float* bh  = (const float*)d_in[3];   // [2048]
    const float* Wph = (const float*)d_in[4];   // [2048,10]
    const float* bp  = (const float*)d_in[5];   // [1,10]
    float* out = (float*)d_out;                 // [1024,10]

    static bool attr_set = false;
    if (!attr_set) {
        hipFuncSetAttribute((const void*)rnn_persist,
                            hipFuncAttributeMaxDynamicSharedMemorySize, 147456);
        attr_set = true;
    }

    prep_whhT<<<dim3(64, 64), 256, 0, stream>>>(Whh);
    rnn_init<<<(B_ * H_ / 4) / 256, 256, 0, stream>>>(x, Whx, bh);
    rnn_persist<<<256, 256, 147456, stream>>>(x, Whx, bh);
    rnn_proj<<<B_, 64, 0, stream>>>(Wph, bp, out, (T_ - 1) & 1);
}